// Round 1
// baseline (258.156 us; speedup 1.0000x reference)
//
#include <hip/hip_runtime.h>
#include <hip/hip_bf16.h>
#include <stdint.h>

typedef __bf16 bf16_t;
typedef __bf16 bf16x8 __attribute__((ext_vector_type(8)));
typedef __bf16 bf16x4 __attribute__((ext_vector_type(4)));
typedef float  f32x4  __attribute__((ext_vector_type(4)));

#define AS_GLOBAL __attribute__((address_space(1)))
#define AS_LDS    __attribute__((address_space(3)))

static constexpr int CCH   = 256;
static constexpr int HP    = 34;
static constexpr int PLANE = HP * HP;   // 1156 padded pixels per image
static constexpr int NPP   = 1024;      // 32*32 pixels per image

// ---------------- BN parameter folding: inv = g/sqrt(v+eps), bias = b - m*inv ----
__global__ void prep_params_k(const float* g1, const float* b1, const float* m1, const float* v1,
                              const float* g2, const float* b2, const float* m2, const float* v2,
                              float* prm) {
  int i = threadIdx.x;  // 256 threads
  float i1 = g1[i] * rsqrtf(v1[i] + 1e-5f);
  prm[i]       = i1;
  prm[256 + i] = b1[i] - m1[i] * i1;
  float i2 = g2[i] * rsqrtf(v2[i] + 1e-5f);
  prm[512 + i] = i2;
  prm[768 + i] = b2[i] - m2[i] * i2;
}

// ---------------- masked weights -> bf16, layout [khw][co][ci] (ci contiguous) ----
__global__ __launch_bounds__(256) void prep_weights_k(const float* __restrict__ w,
                                                      const float* __restrict__ msk,
                                                      bf16_t* __restrict__ out) {
  int idx = blockIdx.x * 256 + threadIdx.x;  // co*256 + ci, grid = 256 blocks
  const float* wp = w + (long)idx * 9;
  const float* mp = msk + (long)idx * 9;
#pragma unroll
  for (int khw = 0; khw < 9; ++khw)
    out[khw * 65536 + idx] = (bf16_t)(wp[khw] * mp[khw]);
}

// ------- relu(bn1(x)) -> bf16, NCHW -> channels-last padded [n][34*34][256] -------
__global__ __launch_bounds__(256) void prep_input_k(const float* __restrict__ x,
                                                    const float* __restrict__ prm,
                                                    bf16_t* __restrict__ t0p) {
  __shared__ __align__(16) bf16_t tile[64 * 256];  // 64 pixels x 256 ci (swizzled)
  const int tid = threadIdx.x;
  const int bid = blockIdx.x;         // 64 images * 16 pixel blocks
  const int n   = bid >> 4;
  const int p0  = (bid & 15) << 6;    // 64 pixels per block
  const int px    = tid & 63;
  const int cbase = tid >> 6;
  // compute + transpose into LDS (16B-block-preserving XOR swizzle on ci offset)
  for (int r = 0; r < 64; ++r) {
    int ci = r * 4 + cbase;
    float v = x[((n * 256 + ci) << 10) + p0 + px];
    float y = fmaxf(v * prm[ci] + prm[256 + ci], 0.f);
    int byte = px * 512 + ((ci * 2) ^ ((px & 7) << 4));
    *(bf16_t*)((char*)tile + byte) = (bf16_t)y;
  }
  __syncthreads();
  // write out contiguous 16B chunks per pixel
  for (int j = 0; j < 8; ++j) {
    int off  = j * 256 + tid;   // 16B-chunk index, 2048 total
    int pix  = off >> 5;        // 0..63
    int c16  = off & 31;        // which 16B (8 ci) of the pixel
    int byte = pix * 512 + ((c16 * 16) ^ ((pix & 7) << 4));
    bf16x8 v = *(const bf16x8*)((char*)tile + byte);
    int p = p0 + pix;
    long gp = ((long)n * PLANE + ((p >> 5) + 1) * HP + (p & 31) + 1) * CCH + c16 * 8;
    *(bf16x8*)(t0p + gp) = v;
  }
}

// ---------------- implicit-GEMM 3x3 conv, bf16 MFMA ----------------
// inp: [64][1156][256] padded channels-last bf16
// wts: [9][256co][256ci] bf16
// EPI 0: out_cl = relu(bn2(conv)) -> padded channels-last bf16
// EPI 1: out_f  = conv + resid    -> NCHW fp32
template <int EPI>
__global__ __launch_bounds__(256, 2) void conv3x3_k(const bf16_t* __restrict__ inp,
                                                    const bf16_t* __restrict__ wts,
                                                    const float* __restrict__ prm,
                                                    const float* __restrict__ resid,
                                                    bf16_t* __restrict__ out_cl,
                                                    float* __restrict__ out_f) {
  __shared__ __align__(128) bf16_t As[2][128 * 32];  // [co][k] rows, swizzled 16B slots
  __shared__ __align__(128) bf16_t Bs[2][128 * 32];  // [pix][k]

  const int tid  = threadIdx.x;
  const int lane = tid & 63;
  const int wid  = tid >> 6;
  const int wm   = wid >> 1;   // 0..1 -> co half
  const int wn   = wid & 1;    // 0..1 -> pixel half

  const int bid = blockIdx.x;       // 1024 blocks
  const int co0 = (bid & 1) << 7;   // 0 / 128
  const int pt  = bid >> 1;         // 512 pixel tiles
  const int n   = pt >> 3;
  const int h0  = (pt & 7) << 2;    // 4 rows of 32 = 128 pixels

  // one swizzle constant serves staging source AND ds_read (derivation in analysis)
  const int swz8   = (((lane & 3) ^ ((lane >> 2) & 3) ^ (lane >> 4)) << 3);
  const int st_row = lane >> 2;  // row within 16-row staging chunk
  const int l15    = lane & 15;

  f32x4 acc[4][4];
#pragma unroll
  for (int i = 0; i < 4; ++i)
#pragma unroll
    for (int j = 0; j < 4; ++j) acc[i][j] = f32x4{0.f, 0.f, 0.f, 0.f};

  auto stage = [&](int buf, int ks) {
    const int khw = ks >> 3;
    const int kh  = khw / 3;
    const int kw  = khw - kh * 3;
    const int ci0 = (ks & 7) << 5;
#pragma unroll
    for (int j = 0; j < 2; ++j) {
      const int c   = wid * 2 + j;       // 1KB chunk index, 16 rows each
      const int row = c * 16 + st_row;
      const bf16_t* ga = wts + ((khw * CCH + co0 + row) * CCH + ci0 + swz8);
      __builtin_amdgcn_global_load_lds((const AS_GLOBAL void*)ga,
                                       (AS_LDS void*)(&As[buf][c * 512]), 16, 0, 0);
      const int pr = row >> 5, pc = row & 31;
      const bf16_t* gb = inp + ((n * PLANE + (h0 + pr + kh) * HP + pc + kw) * CCH + ci0 + swz8);
      __builtin_amdgcn_global_load_lds((const AS_GLOBAL void*)gb,
                                       (AS_LDS void*)(&Bs[buf][c * 512]), 16, 0, 0);
    }
  };

  stage(0, 0);
  int buf = 0;
  for (int ks = 0; ks < 72; ++ks) {   // 9 taps * 8 ci-chunks of 32
    __syncthreads();                   // drains vmcnt -> staged buf readable
    if (ks + 1 < 72) stage(buf ^ 1, ks + 1);
    bf16x8 av[4], bv[4];
#pragma unroll
    for (int mi = 0; mi < 4; ++mi)
      av[mi] = *(const bf16x8*)&As[buf][((wm * 64 + mi * 16 + l15) << 5) + swz8];
#pragma unroll
    for (int ni = 0; ni < 4; ++ni)
      bv[ni] = *(const bf16x8*)&Bs[buf][((wn * 64 + ni * 16 + l15) << 5) + swz8];
#pragma unroll
    for (int mi = 0; mi < 4; ++mi)
#pragma unroll
      for (int ni = 0; ni < 4; ++ni)
        acc[mi][ni] = __builtin_amdgcn_mfma_f32_16x16x32_bf16(av[mi], bv[ni], acc[mi][ni], 0, 0, 0);
    buf ^= 1;
  }

  // C/D layout: col(pixel) = lane&15, row(co) = (lane>>4)*4 + reg
  if (EPI == 0) {
#pragma unroll
    for (int mi = 0; mi < 4; ++mi) {
      const int co_b = co0 + wm * 64 + mi * 16 + ((lane >> 4) << 2);
      const float s0 = prm[co_b], s1 = prm[co_b + 1], s2 = prm[co_b + 2], s3 = prm[co_b + 3];
      const float t0 = prm[256 + co_b], t1 = prm[256 + co_b + 1],
                  t2 = prm[256 + co_b + 2], t3 = prm[256 + co_b + 3];
#pragma unroll
      for (int ni = 0; ni < 4; ++ni) {
        f32x4 v = acc[mi][ni];
        const int p  = (wn << 6) + (ni << 4) + l15;
        const int pr = p >> 5, pc = p & 31;
        bf16x4 pk;
        pk[0] = (bf16_t)fmaxf(v[0] * s0 + t0, 0.f);
        pk[1] = (bf16_t)fmaxf(v[1] * s1 + t1, 0.f);
        pk[2] = (bf16_t)fmaxf(v[2] * s2 + t2, 0.f);
        pk[3] = (bf16_t)fmaxf(v[3] * s3 + t3, 0.f);
        *(bf16x4*)&out_cl[(n * PLANE + (h0 + pr + 1) * HP + pc + 1) * CCH + co_b] = pk;
      }
    }
  } else {
#pragma unroll
    for (int mi = 0; mi < 4; ++mi) {
      const int co_b = co0 + wm * 64 + mi * 16 + ((lane >> 4) << 2);
#pragma unroll
      for (int ni = 0; ni < 4; ++ni) {
        f32x4 v = acc[mi][ni];
        const int p  = (wn << 6) + (ni << 4) + l15;
        const int gp = ((n * CCH + co_b) << 10) + (h0 << 5) + p;
        out_f[gp]        = v[0] + resid[gp];
        out_f[gp + 1024] = v[1] + resid[gp + 1024];
        out_f[gp + 2048] = v[2] + resid[gp + 2048];
        out_f[gp + 3072] = v[3] + resid[gp + 3072];
      }
    }
  }
}

extern "C" void kernel_launch(void* const* d_in, const int* in_sizes, int n_in,
                              void* d_out, int out_size, void* d_ws, size_t ws_size,
                              hipStream_t stream) {
  const float* x  = (const float*)d_in[0];
  const float* g1 = (const float*)d_in[1];
  const float* b1 = (const float*)d_in[2];
  const float* m1 = (const float*)d_in[3];
  const float* v1 = (const float*)d_in[4];
  const float* w1 = (const float*)d_in[5];
  const float* k1 = (const float*)d_in[6];
  const float* g2 = (const float*)d_in[7];
  const float* b2 = (const float*)d_in[8];
  const float* m2 = (const float*)d_in[9];
  const float* v2 = (const float*)d_in[10];
  const float* w2 = (const float*)d_in[11];
  const float* k2 = (const float*)d_in[12];

  char* ws = (char*)d_ws;
  const size_t T0P_B = (size_t)64 * PLANE * CCH * 2;  // 37,879,808
  bf16_t* t0p = (bf16_t*)ws;
  bf16_t* t1p = (bf16_t*)(ws + T0P_B);
  bf16_t* mw1 = (bf16_t*)(ws + 2 * T0P_B);
  bf16_t* mw2 = (bf16_t*)(ws + 2 * T0P_B + 1179648);
  float*  prm = (float*)(ws + 2 * T0P_B + 2 * 1179648);

  // zero pad borders (whole buffers; ws is poisoned before timing)
  hipMemsetAsync(t0p, 0, T0P_B, stream);
  hipMemsetAsync(t1p, 0, T0P_B, stream);

  prep_params_k<<<1, 256, 0, stream>>>(g1, b1, m1, v1, g2, b2, m2, v2, prm);
  prep_weights_k<<<256, 256, 0, stream>>>(w1, k1, mw1);
  prep_weights_k<<<256, 256, 0, stream>>>(w2, k2, mw2);
  prep_input_k<<<1024, 256, 0, stream>>>(x, prm, t0p);

  conv3x3_k<0><<<1024, 256, 0, stream>>>(t0p, mw1, prm + 512, nullptr, t1p, nullptr);
  conv3x3_k<1><<<1024, 256, 0, stream>>>(t1p, mw2, nullptr, x, nullptr, (float*)d_out);
}

// Round 2
// 200.648 us; speedup vs baseline: 1.2866x; 1.2866x over previous
//
#include <hip/hip_runtime.h>
#include <hip/hip_bf16.h>
#include <stdint.h>

typedef __bf16 bf16_t;
typedef __bf16 bf16x8 __attribute__((ext_vector_type(8)));
typedef __bf16 bf16x4 __attribute__((ext_vector_type(4)));
typedef float  f32x4  __attribute__((ext_vector_type(4)));

#define AS_GLOBAL __attribute__((address_space(1)))
#define AS_LDS    __attribute__((address_space(3)))

static constexpr int CCH   = 256;
static constexpr int HP    = 34;
static constexpr int PLANE = HP * HP;   // 1156 padded pixels per image

// ---------------- BN parameter folding ----------------
__global__ void prep_params_k(const float* g1, const float* b1, const float* m1, const float* v1,
                              const float* g2, const float* b2, const float* m2, const float* v2,
                              float* prm) {
  int i = threadIdx.x;
  float i1 = g1[i] * rsqrtf(v1[i] + 1e-5f);
  prm[i]       = i1;
  prm[256 + i] = b1[i] - m1[i] * i1;
  float i2 = g2[i] * rsqrtf(v2[i] + 1e-5f);
  prm[512 + i] = i2;
  prm[768 + i] = b2[i] - m2[i] * i2;
}

// ---------------- masked weights -> bf16, [khw][co][ci] ----------------
__global__ __launch_bounds__(256) void prep_weights_k(const float* __restrict__ w,
                                                      const float* __restrict__ msk,
                                                      bf16_t* __restrict__ out) {
  int idx = blockIdx.x * 256 + threadIdx.x;
  const float* wp = w + (long)idx * 9;
  const float* mp = msk + (long)idx * 9;
#pragma unroll
  for (int khw = 0; khw < 9; ++khw)
    out[khw * 65536 + idx] = (bf16_t)(wp[khw] * mp[khw]);
}

// ---------------- zero only the pad borders of both intermediates ----------------
__global__ __launch_bounds__(256) void zero_borders_k(bf16_t* __restrict__ t0p,
                                                      bf16_t* __restrict__ t1p) {
  const int bid = blockIdx.x;               // 128: image n = bid>>1, buffer = bid&1
  bf16_t* base = ((bid & 1) ? t1p : t0p) + (long)(bid >> 1) * PLANE * CCH;
  for (int i = threadIdx.x; i < 132 * 32; i += 256) {
    int pix = i >> 5, c16 = i & 31;
    int r, col;
    if (pix < 34)       { r = 0;           col = pix; }
    else if (pix < 68)  { r = 33;          col = pix - 34; }
    else if (pix < 100) { r = pix - 68 + 1; col = 0; }
    else                { r = pix - 100 + 1; col = 33; }
    *(f32x4*)&base[(r * HP + col) * CCH + c16 * 8] = f32x4{0.f, 0.f, 0.f, 0.f};
  }
}

// ------- relu(bn1(x)) -> bf16, NCHW -> channels-last padded [n][34*34][256] -------
__global__ __launch_bounds__(256) void prep_input_k(const float* __restrict__ x,
                                                    const float* __restrict__ prm,
                                                    bf16_t* __restrict__ t0p) {
  __shared__ __align__(16) bf16_t tile[64 * 256];
  const int tid = threadIdx.x;
  const int bid = blockIdx.x;
  const int n   = bid >> 4;
  const int p0  = (bid & 15) << 6;
  const int px    = tid & 63;
  const int cbase = tid >> 6;
  for (int r = 0; r < 64; ++r) {
    int ci = r * 4 + cbase;
    float v = x[((n * 256 + ci) << 10) + p0 + px];
    float y = fmaxf(v * prm[ci] + prm[256 + ci], 0.f);
    int byte = px * 512 + ((ci * 2) ^ ((px & 7) << 4));
    *(bf16_t*)((char*)tile + byte) = (bf16_t)y;
  }
  __syncthreads();
  for (int j = 0; j < 8; ++j) {
    int off  = j * 256 + tid;
    int pix  = off >> 5;
    int c16  = off & 31;
    int byte = pix * 512 + ((c16 * 16) ^ ((pix & 7) << 4));
    bf16x8 v = *(const bf16x8*)((char*)tile + byte);
    int p = p0 + pix;
    long gp = ((long)n * PLANE + ((p >> 5) + 1) * HP + (p & 31) + 1) * CCH + c16 * 8;
    *(bf16x8*)(t0p + gp) = v;
  }
}

// ---------------- implicit-GEMM 3x3 conv with tap reuse ----------------
// Outer loop: 8 ci-chunks of 32. Per chunk, stage a 6x34-pixel input patch once;
// inner loop over 9 taps restages only the 8 KB weight tile. B-fragments are read
// from the patch at tap-shifted offsets -> 9x less B-side global traffic.
template <int EPI>
__global__ __launch_bounds__(256, 2) void conv3x3_k(const bf16_t* __restrict__ inp,
                                                    const bf16_t* __restrict__ wts,
                                                    const float* __restrict__ prm,
                                                    const float* __restrict__ resid,
                                                    bf16_t* __restrict__ out_cl,
                                                    float* __restrict__ out_f) {
  __shared__ __align__(128) bf16_t As[2][4096];   // 8 KB: [co128][ci32] swizzled
  __shared__ __align__(128) bf16_t Bs[2][8192];   // 16 KB: patch [r6][c34][ci32] (816 granules + slack)

  const int tid  = threadIdx.x;
  const int lane = tid & 63;
  const int wid  = tid >> 6;
  const int wm   = wid >> 1;
  const int wn   = wid & 1;

  // XCD-aware swizzle: each XCD gets a contiguous chunk of work; co-half pairs adjacent
  const int bid = blockIdx.x;                  // 1024 = 8 XCDs * 128
  const int w   = ((bid & 7) << 7) + (bid >> 3);
  const int co0 = (w & 1) << 7;
  const int pt  = w >> 1;                      // 512 pixel tiles
  const int n   = pt >> 3;
  const int hb  = (pt & 7) << 2;               // padded input rows hb..hb+5 staged

  const int swz8 = (((lane & 3) ^ ((lane >> 2) & 3) ^ (lane >> 4)) << 3);
  const int l15  = lane & 15;

  f32x4 acc[4][4];
#pragma unroll
  for (int i = 0; i < 4; ++i)
#pragma unroll
    for (int j = 0; j < 4; ++j) acc[i][j] = f32x4{0.f, 0.f, 0.f, 0.f};

  auto stageA = [&](int ab, int c, int t) {
    const int ci0 = c << 5;
#pragma unroll
    for (int j = 0; j < 2; ++j) {
      const int ch  = wid * 2 + j;             // 8 chunks of 16 rows
      const int row = ch * 16 + (lane >> 2);
      const bf16_t* ga = wts + ((t * CCH + co0 + row) * CCH + ci0 + swz8);
      __builtin_amdgcn_global_load_lds((const AS_GLOBAL void*)ga,
                                       (AS_LDS void*)(&As[ab][ch * 512]), 16, 0, 0);
    }
  };

  auto stageB = [&](int bb, int c) {
    const int ci0 = c << 5;
#pragma unroll
    for (int j = 0; j < 4; ++j) {
      const int ibase = wid * 4 + j;           // 16 instrs of 64 granules
      int g = (ibase << 6) + lane;
      if (g > 815) g = 815;                    // clamp tail (slack slots never read)
      const int r  = g / 136;                  // row 0..5
      const int rm = g - r * 136;              // col*4 + k16
      const bf16_t* gb = inp + ((n * PLANE + (hb + r) * HP + (rm >> 2)) * CCH + ci0 + ((rm & 3) << 3));
      __builtin_amdgcn_global_load_lds((const AS_GLOBAL void*)gb,
                                       (AS_LDS void*)(&Bs[bb][ibase * 512]), 16, 0, 0);
    }
  };

  stageB(0, 0);
  stageA(0, 0, 0);
  int ab = 0, bb = 0;
  for (int c = 0; c < 8; ++c) {
#pragma unroll
    for (int t = 0; t < 9; ++t) {
      __syncthreads();                         // staged bufs ready (vmcnt drained)
      if (t < 8) stageA(ab ^ 1, c, t + 1);
      else if (c < 7) { stageB(bb ^ 1, c + 1); stageA(ab ^ 1, c + 1, 0); }
      const int kh = t / 3, kw = t - kh * 3;
      bf16x8 av[4], bv[4];
#pragma unroll
      for (int mi = 0; mi < 4; ++mi)
        av[mi] = *(const bf16x8*)&As[ab][((wm * 64 + mi * 16 + l15) << 5) + swz8];
#pragma unroll
      for (int ni = 0; ni < 4; ++ni) {
        const int p  = (wn << 6) + (ni << 4) + l15;
        const int pr = p >> 5, pc = p & 31;
        bv[ni] = *(const bf16x8*)&Bs[bb][((pr + kh) * 136 + (pc + kw) * 4 + (lane >> 4)) * 8];
      }
#pragma unroll
      for (int mi = 0; mi < 4; ++mi)
#pragma unroll
        for (int ni = 0; ni < 4; ++ni)
          acc[mi][ni] = __builtin_amdgcn_mfma_f32_16x16x32_bf16(av[mi], bv[ni], acc[mi][ni], 0, 0, 0);
      ab ^= 1;
    }
    bb ^= 1;
  }

  // C/D layout: col(pixel) = lane&15, row(co) = (lane>>4)*4 + reg
  if (EPI == 0) {
#pragma unroll
    for (int mi = 0; mi < 4; ++mi) {
      const int co_b = co0 + wm * 64 + mi * 16 + ((lane >> 4) << 2);
      const float s0 = prm[co_b], s1 = prm[co_b + 1], s2 = prm[co_b + 2], s3 = prm[co_b + 3];
      const float t0 = prm[256 + co_b], t1 = prm[256 + co_b + 1],
                  t2 = prm[256 + co_b + 2], t3 = prm[256 + co_b + 3];
#pragma unroll
      for (int ni = 0; ni < 4; ++ni) {
        f32x4 v = acc[mi][ni];
        const int p  = (wn << 6) + (ni << 4) + l15;
        const int pr = p >> 5, pc = p & 31;
        bf16x4 pk;
        pk[0] = (bf16_t)fmaxf(v[0] * s0 + t0, 0.f);
        pk[1] = (bf16_t)fmaxf(v[1] * s1 + t1, 0.f);
        pk[2] = (bf16_t)fmaxf(v[2] * s2 + t2, 0.f);
        pk[3] = (bf16_t)fmaxf(v[3] * s3 + t3, 0.f);
        *(bf16x4*)&out_cl[(n * PLANE + (hb + pr + 1) * HP + pc + 1) * CCH + co_b] = pk;
      }
    }
  } else {
#pragma unroll
    for (int mi = 0; mi < 4; ++mi) {
      const int co_b = co0 + wm * 64 + mi * 16 + ((lane >> 4) << 2);
#pragma unroll
      for (int ni = 0; ni < 4; ++ni) {
        f32x4 v = acc[mi][ni];
        const int p  = (wn << 6) + (ni << 4) + l15;
        const int gp = ((n * CCH + co_b) << 10) + (hb << 5) + p;
        out_f[gp]        = v[0] + resid[gp];
        out_f[gp + 1024] = v[1] + resid[gp + 1024];
        out_f[gp + 2048] = v[2] + resid[gp + 2048];
        out_f[gp + 3072] = v[3] + resid[gp + 3072];
      }
    }
  }
}

extern "C" void kernel_launch(void* const* d_in, const int* in_sizes, int n_in,
                              void* d_out, int out_size, void* d_ws, size_t ws_size,
                              hipStream_t stream) {
  const float* x  = (const float*)d_in[0];
  const float* g1 = (const float*)d_in[1];
  const float* b1 = (const float*)d_in[2];
  const float* m1 = (const float*)d_in[3];
  const float* v1 = (const float*)d_in[4];
  const float* w1 = (const float*)d_in[5];
  const float* k1 = (const float*)d_in[6];
  const float* g2 = (const float*)d_in[7];
  const float* b2 = (const float*)d_in[8];
  const float* m2 = (const float*)d_in[9];
  const float* v2 = (const float*)d_in[10];
  const float* w2 = (const float*)d_in[11];
  const float* k2 = (const float*)d_in[12];

  char* ws = (char*)d_ws;
  const size_t T0P_B = (size_t)64 * PLANE * CCH * 2;
  bf16_t* t0p = (bf16_t*)ws;
  bf16_t* t1p = (bf16_t*)(ws + T0P_B);
  bf16_t* mw1 = (bf16_t*)(ws + 2 * T0P_B);
  bf16_t* mw2 = (bf16_t*)(ws + 2 * T0P_B + 1179648);
  float*  prm = (float*)(ws + 2 * T0P_B + 2 * 1179648);

  prep_params_k<<<1, 256, 0, stream>>>(g1, b1, m1, v1, g2, b2, m2, v2, prm);
  zero_borders_k<<<128, 256, 0, stream>>>(t0p, t1p);
  prep_weights_k<<<256, 256, 0, stream>>>(w1, k1, mw1);
  prep_weights_k<<<256, 256, 0, stream>>>(w2, k2, mw2);
  prep_input_k<<<1024, 256, 0, stream>>>(x, prm, t0p);

  conv3x3_k<0><<<1024, 256, 0, stream>>>(t0p, mw1, prm + 512, nullptr, t1p, nullptr);
  conv3x3_k<1><<<1024, 256, 0, stream>>>(t1p, mw2, nullptr, x, nullptr, (float*)d_out);
}